// Round 17
// baseline (238.276 us; speedup 1.0000x reference)
//
#include <hip/hip_runtime.h>

constexpr int Bb = 4;
constexpr int Ss = 2048;
constexpr int QSTR = 1536;   // combined qkv row stride (g 0..767, t 768..1535)

typedef __bf16 bf16x8 __attribute__((ext_vector_type(8)));
typedef __bf16 bf16x4 __attribute__((ext_vector_type(4)));
typedef float  f32x4  __attribute__((ext_vector_type(4)));

// async global->LDS, 16B per lane; dest = wave-uniform base + lane*16
__device__ __forceinline__ void glds16(const void* g, void* l) {
    __builtin_amdgcn_global_load_lds(
        (const __attribute__((address_space(1))) unsigned int*)g,
        (__attribute__((address_space(3))) unsigned int*)l, 16, 0, 0);
}

// ---------------------------------------------------------------------------
// convert_all: fp32 -> bf16 for x and the 8 weight matrices, one launch.
// ---------------------------------------------------------------------------
struct CvtArgs {
    const float* src[9];
    __bf16* dst[9];
    int start[10];
};

__global__ __launch_bounds__(256) void convert_all(CvtArgs a)
{
    int e = 0;
    const int bid = blockIdx.x;
#pragma unroll
    for (int i = 0; i < 8; i++) if (bid >= a.start[i + 1]) e = i + 1;
    const int idx = (bid - a.start[e]) * 256 + threadIdx.x;
    const float* s = a.src[e];
    float4 v0 = *(const float4*)&s[(size_t)idx * 8];
    float4 v1 = *(const float4*)&s[(size_t)idx * 8 + 4];
    bf16x8 o;
    o[0] = (__bf16)v0.x; o[1] = (__bf16)v0.y; o[2] = (__bf16)v0.z; o[3] = (__bf16)v0.w;
    o[4] = (__bf16)v1.x; o[5] = (__bf16)v1.y; o[6] = (__bf16)v1.z; o[7] = (__bf16)v1.w;
    *(bf16x8*)&a.dst[e][(size_t)idx * 8] = o;
}

// ---------------------------------------------------------------------------
// gemm_small: BM=32, BN=64, BK=128; 4 waves as 2(m)x2(n), each 16x32.
// lda decouples A row stride from K. Second-weight select: blocks with
// blockIdx.x >= nsplit use W1/bias1, A0+aoff1, coff1. Used for ALL GEMMs
// (QKV included): occupancy beats per-block MFMA density at these shapes.
// ---------------------------------------------------------------------------
template<bool SILU, bool OUT_BF16>
__global__ __launch_bounds__(256) void gemm_small(
    const __bf16* __restrict__ A0, const __bf16* __restrict__ W0,
    const float* __restrict__ bias0, const __bf16* __restrict__ W1,
    const float* __restrict__ bias1, int nsplit, int aoff1, int coff1,
    void* __restrict__ C, int lda, int K, int ldc)
{
    __shared__ __bf16 As[32 * 128];
    __shared__ __bf16 Ws[64 * 128];
    const int tid = threadIdx.x;
    const int lane = tid & 63;
    const int wv = tid >> 6;
    const int wm = (wv >> 1) * 16;
    const int wn = (wv & 1) * 32;
    const int qrow = lane & 15;
    const int quad = lane >> 4;
    const bool second = (int)blockIdx.x >= nsplit;
    const int bx = second ? (blockIdx.x - nsplit) : blockIdx.x;
    const __bf16* A = second ? (A0 + aoff1) : A0;
    const __bf16* W = second ? W1 : W0;
    const float* bias = second ? bias1 : bias0;
    const int coff = second ? coff1 : 0;
    const int n0 = bx * 64;
    const int m0 = blockIdx.y * 32;

    f32x4 acc[2];
    acc[0] = {0.f, 0.f, 0.f, 0.f};
    acc[1] = {0.f, 0.f, 0.f, 0.f};

    for (int k0 = 0; k0 < K; k0 += 128) {
        __syncthreads();
#pragma unroll
        for (int i = 0; i < 2; i++) {
            const int c = (wv * 2 + i) * 64 + lane;
            const int row = c >> 4, s = c & 15;
            const int gs = ((s & 8) | ((s ^ row) & 7)) * 8;
            glds16(&A[(size_t)(m0 + row) * lda + k0 + gs], &As[(wv * 2 + i) * 512]);
        }
#pragma unroll
        for (int i = 0; i < 4; i++) {
            const int c = (wv * 4 + i) * 64 + lane;
            const int row = c >> 4, s = c & 15;
            const int gs = ((s & 8) | ((s ^ row) & 7)) * 8;
            glds16(&W[(size_t)(n0 + row) * K + k0 + gs], &Ws[(wv * 4 + i) * 512]);
        }
        __syncthreads();
#pragma unroll
        for (int ksub = 0; ksub < 4; ksub++) {
            const int gl = ksub * 4 + quad;
            bf16x8 af, bf[2];
            {
                const int row = wm + qrow;
                const int s = (gl & 8) | ((gl ^ row) & 7);
                af = *(const bf16x8*)&As[row * 128 + s * 8];
            }
#pragma unroll
            for (int ni = 0; ni < 2; ni++) {
                const int row = wn + ni * 16 + qrow;
                const int s = (gl & 8) | ((gl ^ row) & 7);
                bf[ni] = *(const bf16x8*)&Ws[row * 128 + s * 8];
            }
#pragma unroll
            for (int ni = 0; ni < 2; ni++)
                acc[ni] = __builtin_amdgcn_mfma_f32_16x16x32_bf16(
                    af, bf[ni], acc[ni], 0, 0, 0);
        }
    }

    float bz[2];
#pragma unroll
    for (int ni = 0; ni < 2; ni++) bz[ni] = bias[n0 + wn + ni * 16 + qrow];

#pragma unroll
    for (int r = 0; r < 4; r++) {
        const int row = m0 + wm + quad * 4 + r;
#pragma unroll
        for (int ni = 0; ni < 2; ni++) {
            float v = acc[ni][r] + bz[ni];
            if (SILU) v = v / (1.f + __expf(-v));
            const int col = coff + n0 + wn + ni * 16 + qrow;
            if (OUT_BF16)
                ((__bf16*)C)[(size_t)row * ldc + col] = (__bf16)v;
            else
                ((float*)C)[(size_t)row * ldc + col] = v;
        }
    }
}

// ---------------------------------------------------------------------------
// attn_fused: 512-thread blocks.
// Blocks 0..1023: global MHA split-K x2 partials, 8 waves x 16 q = 128 q/blk,
//   16 key-chunks/block. Single-barrier double-buffered K-loop (LDS 35.8 KB;
//   4 blocks/CU is thread-capped so the double buffer costs no occupancy).
// Blocks 1024..5119: local window-5 MHA -> acat cols 256-511.
// ---------------------------------------------------------------------------
__global__ __launch_bounds__(512) void attn_fused(
    const __bf16* __restrict__ qkv, __bf16* __restrict__ Op,
    float* __restrict__ Lp, __bf16* __restrict__ acat)
{
    __shared__ __bf16 Kl[2][64 * 32];
    __shared__ __bf16 Vt[2][32 * 72];
    __shared__ __bf16 Pl[8][16 * 72];

    const int t = threadIdx.x;
    const int lane = t & 63;
    const int wv = t >> 6;          // 0..7

    if (blockIdx.x < 1024) {
        const int bid = blockIdx.x;
        const int sp = bid & 1;
        const int qc = (bid >> 1) & 15;
        const int h  = (bid >> 5) & 7;
        const int b  = bid >> 8;
        const int bS = b * Ss;
        const int q0 = qc * 128;

        const int qrow = lane & 15;
        const int quad = lane >> 4;
        const float cQ = 1.4426950408889634f * 0.17677669529663687f; // log2e/sqrt(32)

        bf16x8 qf;
        {
            bf16x8 qraw = *(const bf16x8*)(qkv +
                (size_t)(bS + q0 + wv * 16 + qrow) * QSTR + h * 32 + quad * 8);
#pragma unroll
            for (int i = 0; i < 8; i++) qf[i] = (__bf16)((float)qraw[i] * cQ);
        }
        bf16x8 ones;
#pragma unroll
        for (int i = 0; i < 8; i++) ones[i] = (__bf16)1.0f;

        f32x4 o0 = {0.f, 0.f, 0.f, 0.f};
        f32x4 o1 = {0.f, 0.f, 0.f, 0.f};
        f32x4 lac = {0.f, 0.f, 0.f, 0.f};
        const f32x4 z = {0.f, 0.f, 0.f, 0.f};

        const int kc_c = wv * 64 + lane;
        const int kkey = kc_c >> 2, kdg = kc_c & 3;
        const int vkey = t & 63, vq = t >> 6;   // V: key, dim group of 4
        const int kc0 = sp * 16;

        // prologue: prefetch chunk 0 (V into regs, K via glds into Kl[0])
        bf16x4 vreg = *(const bf16x4*)(qkv +
            (size_t)(bS + kc0 * 64 + vkey) * QSTR + 512 + h * 32 + vq * 4);
        if (wv < 4)
            glds16(qkv + (size_t)(bS + kc0 * 64 + kkey) * QSTR + 256 + h * 32 + kdg * 8,
                   &Kl[0][wv * 512]);

        for (int i = 0; i < 16; i++) {
            const int cur = i & 1;
#pragma unroll
            for (int e = 0; e < 4; e++) Vt[cur][(vq * 4 + e) * 72 + vkey] = vreg[e];
            __syncthreads();
            const int nx = (i < 15) ? (kc0 + i + 1) : (kc0 + 15);
            vreg = *(const bf16x4*)(qkv +
                (size_t)(bS + nx * 64 + vkey) * QSTR + 512 + h * 32 + vq * 4);
            if (i < 15 && wv < 4)
                glds16(qkv + (size_t)(bS + nx * 64 + kkey) * QSTR + 256 + h * 32 + kdg * 8,
                       &Kl[1 - cur][wv * 512]);

            f32x4 s[4];
#pragma unroll
            for (int kg = 0; kg < 4; kg++) {
                bf16x8 kf = *(const bf16x8*)&Kl[cur][(kg * 16 + qrow) * 32 + quad * 8];
                s[kg] = __builtin_amdgcn_mfma_f32_16x16x32_bf16(kf, qf, z, 0, 0, 0);
            }
#pragma unroll
            for (int kg = 0; kg < 4; kg++) {
                bf16x4 pk;
                pk[0] = (__bf16)exp2f(s[kg][0]);
                pk[1] = (__bf16)exp2f(s[kg][1]);
                pk[2] = (__bf16)exp2f(s[kg][2]);
                pk[3] = (__bf16)exp2f(s[kg][3]);
                *(bf16x4*)&Pl[wv][qrow * 72 + kg * 16 + quad * 4] = pk;
            }
            bf16x8 pf0 = *(const bf16x8*)&Pl[wv][qrow * 72 + quad * 8];
            bf16x8 pf1 = *(const bf16x8*)&Pl[wv][qrow * 72 + 32 + quad * 8];
            bf16x8 vf00 = *(const bf16x8*)&Vt[cur][qrow * 72 + quad * 8];
            bf16x8 vf01 = *(const bf16x8*)&Vt[cur][qrow * 72 + 32 + quad * 8];
            bf16x8 vf10 = *(const bf16x8*)&Vt[cur][(16 + qrow) * 72 + quad * 8];
            bf16x8 vf11 = *(const bf16x8*)&Vt[cur][(16 + qrow) * 72 + 32 + quad * 8];
            o0 = __builtin_amdgcn_mfma_f32_16x16x32_bf16(vf00, pf0, o0, 0, 0, 0);
            o1 = __builtin_amdgcn_mfma_f32_16x16x32_bf16(vf10, pf0, o1, 0, 0, 0);
            lac = __builtin_amdgcn_mfma_f32_16x16x32_bf16(ones, pf0, lac, 0, 0, 0);
            o0 = __builtin_amdgcn_mfma_f32_16x16x32_bf16(vf01, pf1, o0, 0, 0, 0);
            o1 = __builtin_amdgcn_mfma_f32_16x16x32_bf16(vf11, pf1, o1, 0, 0, 0);
            lac = __builtin_amdgcn_mfma_f32_16x16x32_bf16(ones, pf1, lac, 0, 0, 0);
        }

        const int gid = (b * 8 + h) * 2048 + q0 + wv * 16 + qrow;
        __bf16* po = Op + (size_t)sp * 2097152 + (size_t)gid * 32;
        bf16x4 w0, w1;
#pragma unroll
        for (int r = 0; r < 4; r++) { w0[r] = (__bf16)o0[r]; w1[r] = (__bf16)o1[r]; }
        *(bf16x4*)&po[quad * 4]      = w0;
        *(bf16x4*)&po[16 + quad * 4] = w1;
        if (quad == 0) Lp[sp * 65536 + gid] = lac[0];
    } else {
        const int w = (blockIdx.x - 1024) * 8 + wv;
        const int b = w >> 13;
        const int rem = w & 8191;
        const int s = rem >> 2;
        const int h = rem & 3;

        const float q = (float)qkv[(size_t)(b * Ss + s) * QSTR + 768 + h * 64 + lane];
        float sc[5], vv[5];
#pragma unroll
        for (int j = 0; j < 5; j++) {
            int pos = s + j - 2;
            bool valid = (pos >= 0) && (pos < Ss);
            int cpos = valid ? pos : 0;
            const size_t rb = (size_t)(b * Ss + cpos) * QSTR;
            float kj = valid ? (float)qkv[rb + 1024 + h * 64 + lane] : 0.f;
            vv[j] = valid ? (float)qkv[rb + 1280 + h * 64 + lane] : 0.f;
            float p = q * kj;
#pragma unroll
            for (int off = 32; off > 0; off >>= 1) p += __shfl_xor(p, off, 64);
            sc[j] = valid ? p * 0.125f : -1e30f;
        }
        float m = sc[0];
#pragma unroll
        for (int j = 1; j < 5; j++) m = fmaxf(m, sc[j]);
        float l = 0.f, o = 0.f;
#pragma unroll
        for (int j = 0; j < 5; j++) {
            float p = __expf(sc[j] - m);
            l += p; o += p * vv[j];
        }
        acat[(size_t)(b * Ss + s) * 512 + 256 + h * 64 + lane] = (__bf16)(o / l);
    }
}

// ---------------------------------------------------------------------------
// attn_combine: 2 bf16 split partials -> acat cols 0-255.
// ---------------------------------------------------------------------------
__global__ __launch_bounds__(256) void attn_combine(
    const __bf16* __restrict__ Op, const float* __restrict__ Lp,
    __bf16* __restrict__ acat)
{
    const int t = blockIdx.x * 256 + threadIdx.x;   // 0 .. 524287
    const int gid = t >> 3;
    const int dg = t & 7;
    const int b = gid >> 14;
    const int h = (gid >> 11) & 7;
    const int q = gid & 2047;

    const float li = 1.f / (Lp[gid] + Lp[65536 + gid]);
    const __bf16* base = Op + (size_t)gid * 32 + dg * 4;
    bf16x4 a0 = *(const bf16x4*)&base[0];
    bf16x4 a1 = *(const bf16x4*)&base[2097152];
    bf16x4 r;
#pragma unroll
    for (int i = 0; i < 4; i++)
        r[i] = (__bf16)(((float)a0[i] + (float)a1[i]) * li);
    *(bf16x4*)&acat[(size_t)(b * Ss + q) * 512 + h * 32 + dg * 4] = r;
}

// ---------------------------------------------------------------------------
// out = LayerNorm(a + r) * g + be over last dim (256). Wave per token.
// a fp32, r bf16. ob optional bf16 copy.
// ---------------------------------------------------------------------------
__global__ __launch_bounds__(256) void ln_residual(
    const float* __restrict__ a, const __bf16* __restrict__ r,
    const float* __restrict__ g, const float* __restrict__ be,
    float* __restrict__ out, __bf16* __restrict__ ob)
{
    const int lane = threadIdx.x & 63;
    const int tok = blockIdx.x * 4 + (threadIdx.x >> 6);
    float4 xa = ((const float4*)a)[(size_t)tok * 64 + lane];
    bf16x4 xr = *(const bf16x4*)&r[(size_t)tok * 256 + lane * 4];
    float4 x;
    x.x = xa.x + (float)xr[0]; x.y = xa.y + (float)xr[1];
    x.z = xa.z + (float)xr[2]; x.w = xa.w + (float)xr[3];
    float sum = x.x + x.y + x.z + x.w;
#pragma unroll
    for (int off = 32; off > 0; off >>= 1) sum += __shfl_xor(sum, off, 64);
    float mu = sum * (1.f / 256.f);
    float4 c;
    c.x = x.x - mu; c.y = x.y - mu; c.z = x.z - mu; c.w = x.w - mu;
    float sq = c.x * c.x + c.y * c.y + c.z * c.z + c.w * c.w;
#pragma unroll
    for (int off = 32; off > 0; off >>= 1) sq += __shfl_xor(sq, off, 64);
    float rs = rsqrtf(sq * (1.f / 256.f) + 1e-5f);
    float4 gg = ((const float4*)g)[lane];
    float4 bb = ((const float4*)be)[lane];
    float4 o;
    o.x = c.x * rs * gg.x + bb.x; o.y = c.y * rs * gg.y + bb.y;
    o.z = c.z * rs * gg.z + bb.z; o.w = c.w * rs * gg.w + bb.w;
    ((float4*)out)[(size_t)tok * 64 + lane] = o;
    if (ob) {
        bf16x4 hh;
        hh[0] = (__bf16)o.x; hh[1] = (__bf16)o.y; hh[2] = (__bf16)o.z; hh[3] = (__bf16)o.w;
        *(bf16x4*)&ob[(size_t)tok * 256 + lane * 4] = hh;
    }
}

// ---------------------------------------------------------------------------
extern "C" void kernel_launch(void* const* d_in, const int* in_sizes, int n_in,
                              void* d_out, int out_size, void* d_ws, size_t ws_size,
                              hipStream_t stream)
{
    const float* x      = (const float*)d_in[0];
    const float* g_in_w = (const float*)d_in[1];
    const float* g_in_b = (const float*)d_in[2];
    const float* g_out_w= (const float*)d_in[3];
    const float* g_out_b= (const float*)d_in[4];
    const float* t_in_w = (const float*)d_in[5];
    const float* t_in_b = (const float*)d_in[6];
    const float* t_out_w= (const float*)d_in[7];
    const float* t_out_b= (const float*)d_in[8];
    const float* fus_w1 = (const float*)d_in[9];
    const float* fus_b1 = (const float*)d_in[10];
    const float* fus_w2 = (const float*)d_in[11];
    const float* fus_b2 = (const float*)d_in[12];
    const float* ffn_w1 = (const float*)d_in[13];
    const float* ffn_b1 = (const float*)d_in[14];
    const float* ffn_w2 = (const float*)d_in[15];
    const float* ffn_b2 = (const float*)d_in[16];
    const float* gn_g   = (const float*)d_in[17];
    const float* gn_b   = (const float*)d_in[18];
    const float* fn_g   = (const float*)d_in[19];
    const float* fn_b   = (const float*)d_in[20];
    float* out = (float*)d_out;
    float* ws  = (float*)d_ws;

    // ws layout in f32 slots (peak < 19,464,192 slots = 77.9 MB; 84 MB safe)
    __bf16* xb     = (__bf16*)(ws);                 // [0, 1048576)
    __bf16* wb     = (__bf16*)(ws + 1048576);       // [1048576, 1638400)
    __bf16* qkvgl  = (__bf16*)(ws + 1638400);       // [1638400, 7929856)  8192x1536
    __bf16* acat   = (__bf16*)(ws + 7929856);       // [7929856, 10027008) 8192x512
    __bf16* fcomb  = (__bf16*)(ws + 10027008);      // [10027008, 12124160) 8192x512
    __bf16* h1     = (__bf16*)(ws + 12124160);      // [12124160, 14221312) 8192x512
    __bf16* xfb    = (__bf16*)(ws + 14221312);      // [14221312, 15269888) 8192x256
    float*  x2     = ws + 16318464;                 // [16318464, 18415616) fp32
    __bf16* x2b    = (__bf16*)(ws + 18415616);      // [18415616, 19464192)
    __bf16* h2     = h1;                            // reuse
    __bf16* xffb   = xfb;                           // reuse
    // attention partials: live only between attn_fused and attn_combine.
    __bf16* Op = (__bf16*)(ws + 10027008);          // 2x65536x32 bf16 over fcomb+h1
    float*  Lp = ws + 18415616;                     // 2x65536 fp32 over x2b

    __bf16* w_gin  = wb;              // [1536x256] combined (g rows 0-767, t 768-1535)
    __bf16* w_tin  = wb + 196608;     // t rows of the combined QKV weight
    __bf16* w_gout = wb + 393216;
    __bf16* w_tout = wb + 458752;
    __bf16* w_f1   = wb + 524288;
    __bf16* w_f2   = wb + 786432;
    __bf16* w_n1   = wb + 917504;
    __bf16* w_n2   = wb + 1048576;

    CvtArgs ca;
    ca.src[0] = x;      ca.dst[0] = xb;
    ca.src[1] = g_in_w; ca.dst[1] = w_gin;
    ca.src[2] = t_in_w; ca.dst[2] = w_tin;
    ca.src[3] = g_out_w;ca.dst[3] = w_gout;
    ca.src[4] = t_out_w;ca.dst[4] = w_tout;
    ca.src[5] = fus_w1; ca.dst[5] = w_f1;
    ca.src[6] = fus_w2; ca.dst[6] = w_f2;
    ca.src[7] = ffn_w1; ca.dst[7] = w_n1;
    ca.src[8] = ffn_w2; ca.dst[8] = w_n2;
    int st[10] = {0, 1024, 1120, 1216, 1248, 1280, 1408, 1472, 1536, 1600};
    for (int i = 0; i < 10; i++) ca.start[i] = st[i];

    convert_all<<<dim3(1600), 256, 0, stream>>>(ca);

    // QKV projection via small tiles: M=8192, N=1536 (g cols 0-767 blocks 0-11,
    // t cols 768-1535 blocks 12-23), K=256 -> qkvgl. Grid 6144 blocks.
    gemm_small<false, true><<<dim3(24, 256), 256, 0, stream>>>(
        xb, w_gin, g_in_b, w_tin, t_in_b, 12, 0, 768, qkvgl, 256, 256, QSTR);
    // Global attention partials split-K x2 (blocks 0-1023) + local (1024-5119)
    attn_fused<<<dim3(5120), 512, 0, stream>>>(qkvgl, Op, Lp, acat);
    // Combine partials -> acat cols 0-255
    attn_combine<<<dim3(2048), 256, 0, stream>>>(Op, Lp, acat);
    // Fused output projections (both halves in one launch) into fcomb
    gemm_small<false, true><<<dim3(8, 256), 256, 0, stream>>>(
        acat, w_gout, g_out_b, w_tout, t_out_b, 4, 256, 256, fcomb, 512, 256, 512);
    // Fusion MLP
    gemm_small<true,  true><<<dim3(8, 256), 256, 0, stream>>>(
        fcomb, w_f1, fus_b1, w_f1, fus_b1, 1 << 30, 0, 0, h1, 512, 512, 512);
    gemm_small<false, true><<<dim3(4, 256), 256, 0, stream>>>(
        h1, w_f2, fus_b2, w_f2, fus_b2, 1 << 30, 0, 0, xfb, 512, 512, 256);
    ln_residual<<<dim3(2048), 256, 0, stream>>>(x, xfb, gn_g, gn_b, x2, x2b);
    // FFN
    gemm_small<true,  true><<<dim3(8, 256), 256, 0, stream>>>(
        x2b, w_n1, ffn_b1, w_n1, ffn_b1, 1 << 30, 0, 0, h2, 256, 256, 512);
    gemm_small<false, true><<<dim3(4, 256), 256, 0, stream>>>(
        h2, w_n2, ffn_b2, w_n2, ffn_b2, 1 << 30, 0, 0, xffb, 512, 512, 256);
    ln_residual<<<dim3(2048), 256, 0, stream>>>(x2, xffb, fn_g, fn_b, out, nullptr);
}

// Round 18
// 232.299 us; speedup vs baseline: 1.0257x; 1.0257x over previous
//
#include <hip/hip_runtime.h>

constexpr int Bb = 4;
constexpr int Ss = 2048;
constexpr int QSTR = 1536;   // combined qkv row stride (g 0..767, t 768..1535)

typedef __bf16 bf16x8 __attribute__((ext_vector_type(8)));
typedef __bf16 bf16x4 __attribute__((ext_vector_type(4)));
typedef float  f32x4  __attribute__((ext_vector_type(4)));

// async global->LDS, 16B per lane; dest = wave-uniform base + lane*16
__device__ __forceinline__ void glds16(const void* g, void* l) {
    __builtin_amdgcn_global_load_lds(
        (const __attribute__((address_space(1))) unsigned int*)g,
        (__attribute__((address_space(3))) unsigned int*)l, 16, 0, 0);
}

// ---------------------------------------------------------------------------
// convert_all: fp32 -> bf16 for x and the 8 weight matrices, one launch.
// ---------------------------------------------------------------------------
struct CvtArgs {
    const float* src[9];
    __bf16* dst[9];
    int start[10];
};

__global__ __launch_bounds__(256) void convert_all(CvtArgs a)
{
    int e = 0;
    const int bid = blockIdx.x;
#pragma unroll
    for (int i = 0; i < 8; i++) if (bid >= a.start[i + 1]) e = i + 1;
    const int idx = (bid - a.start[e]) * 256 + threadIdx.x;
    const float* s = a.src[e];
    float4 v0 = *(const float4*)&s[(size_t)idx * 8];
    float4 v1 = *(const float4*)&s[(size_t)idx * 8 + 4];
    bf16x8 o;
    o[0] = (__bf16)v0.x; o[1] = (__bf16)v0.y; o[2] = (__bf16)v0.z; o[3] = (__bf16)v0.w;
    o[4] = (__bf16)v1.x; o[5] = (__bf16)v1.y; o[6] = (__bf16)v1.z; o[7] = (__bf16)v1.w;
    *(bf16x8*)&a.dst[e][(size_t)idx * 8] = o;
}

// ---------------------------------------------------------------------------
// gemm128: BM=BN=128, BK=64; 4 waves each 64x64 (4x4 MFMA accs). For QKV.
// XOR swizzle: LDS slot (row,g) holds global chunk (row, g^(row&7)).
// 768 blocks = 3/CU: adequately fed; higher MFMA density wins at this shape
// (verified R16 vs R17).
// ---------------------------------------------------------------------------
__global__ __launch_bounds__(256) void gemm128(
    const __bf16* __restrict__ A, const __bf16* __restrict__ W,
    const float* __restrict__ bias, const float* __restrict__ bias2, int bsplit,
    __bf16* __restrict__ C, int K, int ldc)
{
    __shared__ __bf16 As[128 * 64];
    __shared__ __bf16 Ws[128 * 64];
    const int tid = threadIdx.x;
    const int lane = tid & 63;
    const int wv = tid >> 6;
    const int wm = (wv >> 1) * 64;
    const int wn = (wv & 1) * 64;
    const int qrow = lane & 15;
    const int quad = lane >> 4;
    const int n0 = blockIdx.x * 128;
    const int m0 = blockIdx.y * 128;

    f32x4 acc[4][4];
#pragma unroll
    for (int i = 0; i < 4; i++)
#pragma unroll
        for (int j = 0; j < 4; j++) acc[i][j] = {0.f, 0.f, 0.f, 0.f};

    for (int k0 = 0; k0 < K; k0 += 64) {
        __syncthreads();
#pragma unroll
        for (int i = 0; i < 4; i++) {
            const int c = (wv * 4 + i) * 64 + lane;
            const int row = c >> 3, g = c & 7;
            const int gs = (g ^ (row & 7)) * 8;
            glds16(&A[(size_t)(m0 + row) * K + k0 + gs], &As[(wv * 4 + i) * 512]);
            glds16(&W[(size_t)(n0 + row) * K + k0 + gs], &Ws[(wv * 4 + i) * 512]);
        }
        __syncthreads();
#pragma unroll
        for (int ksub = 0; ksub < 2; ksub++) {
            const int gl = ksub * 4 + quad;
            bf16x8 af[4], bf[4];
#pragma unroll
            for (int mi = 0; mi < 4; mi++) {
                const int row = wm + mi * 16 + qrow;
                af[mi] = *(const bf16x8*)&As[row * 64 + (gl ^ (row & 7)) * 8];
            }
#pragma unroll
            for (int ni = 0; ni < 4; ni++) {
                const int row = wn + ni * 16 + qrow;
                bf[ni] = *(const bf16x8*)&Ws[row * 64 + (gl ^ (row & 7)) * 8];
            }
#pragma unroll
            for (int mi = 0; mi < 4; mi++)
#pragma unroll
                for (int ni = 0; ni < 4; ni++)
                    acc[mi][ni] = __builtin_amdgcn_mfma_f32_16x16x32_bf16(
                        af[mi], bf[ni], acc[mi][ni], 0, 0, 0);
        }
    }

    float bz[4];
#pragma unroll
    for (int ni = 0; ni < 4; ni++) {
        const int n = n0 + wn + ni * 16 + qrow;
        bz[ni] = (n < bsplit) ? bias[n] : bias2[n - bsplit];
    }
#pragma unroll
    for (int mi = 0; mi < 4; mi++)
#pragma unroll
        for (int r = 0; r < 4; r++) {
            const int row = m0 + wm + mi * 16 + quad * 4 + r;
#pragma unroll
            for (int ni = 0; ni < 4; ni++) {
                float v = acc[mi][ni][r] + bz[ni];
                C[(size_t)row * ldc + n0 + wn + ni * 16 + qrow] = (__bf16)v;
            }
        }
}

// ---------------------------------------------------------------------------
// gemm_small: BM=32, BN=64, BK=128; 4 waves as 2(m)x2(n), each 16x32.
// lda decouples A row stride from K. Second-weight select: blocks with
// blockIdx.x >= nsplit use W1/bias1, A0+aoff1, coff1.
// ---------------------------------------------------------------------------
template<bool SILU, bool OUT_BF16>
__global__ __launch_bounds__(256) void gemm_small(
    const __bf16* __restrict__ A0, const __bf16* __restrict__ W0,
    const float* __restrict__ bias0, const __bf16* __restrict__ W1,
    const float* __restrict__ bias1, int nsplit, int aoff1, int coff1,
    void* __restrict__ C, int lda, int K, int ldc)
{
    __shared__ __bf16 As[32 * 128];
    __shared__ __bf16 Ws[64 * 128];
    const int tid = threadIdx.x;
    const int lane = tid & 63;
    const int wv = tid >> 6;
    const int wm = (wv >> 1) * 16;
    const int wn = (wv & 1) * 32;
    const int qrow = lane & 15;
    const int quad = lane >> 4;
    const bool second = (int)blockIdx.x >= nsplit;
    const int bx = second ? (blockIdx.x - nsplit) : blockIdx.x;
    const __bf16* A = second ? (A0 + aoff1) : A0;
    const __bf16* W = second ? W1 : W0;
    const float* bias = second ? bias1 : bias0;
    const int coff = second ? coff1 : 0;
    const int n0 = bx * 64;
    const int m0 = blockIdx.y * 32;

    f32x4 acc[2];
    acc[0] = {0.f, 0.f, 0.f, 0.f};
    acc[1] = {0.f, 0.f, 0.f, 0.f};

    for (int k0 = 0; k0 < K; k0 += 128) {
        __syncthreads();
#pragma unroll
        for (int i = 0; i < 2; i++) {
            const int c = (wv * 2 + i) * 64 + lane;
            const int row = c >> 4, s = c & 15;
            const int gs = ((s & 8) | ((s ^ row) & 7)) * 8;
            glds16(&A[(size_t)(m0 + row) * lda + k0 + gs], &As[(wv * 2 + i) * 512]);
        }
#pragma unroll
        for (int i = 0; i < 4; i++) {
            const int c = (wv * 4 + i) * 64 + lane;
            const int row = c >> 4, s = c & 15;
            const int gs = ((s & 8) | ((s ^ row) & 7)) * 8;
            glds16(&W[(size_t)(n0 + row) * K + k0 + gs], &Ws[(wv * 4 + i) * 512]);
        }
        __syncthreads();
#pragma unroll
        for (int ksub = 0; ksub < 4; ksub++) {
            const int gl = ksub * 4 + quad;
            bf16x8 af, bf[2];
            {
                const int row = wm + qrow;
                const int s = (gl & 8) | ((gl ^ row) & 7);
                af = *(const bf16x8*)&As[row * 128 + s * 8];
            }
#pragma unroll
            for (int ni = 0; ni < 2; ni++) {
                const int row = wn + ni * 16 + qrow;
                const int s = (gl & 8) | ((gl ^ row) & 7);
                bf[ni] = *(const bf16x8*)&Ws[row * 128 + s * 8];
            }
#pragma unroll
            for (int ni = 0; ni < 2; ni++)
                acc[ni] = __builtin_amdgcn_mfma_f32_16x16x32_bf16(
                    af, bf[ni], acc[ni], 0, 0, 0);
        }
    }

    float bz[2];
#pragma unroll
    for (int ni = 0; ni < 2; ni++) bz[ni] = bias[n0 + wn + ni * 16 + qrow];

#pragma unroll
    for (int r = 0; r < 4; r++) {
        const int row = m0 + wm + quad * 4 + r;
#pragma unroll
        for (int ni = 0; ni < 2; ni++) {
            float v = acc[ni][r] + bz[ni];
            if (SILU) v = v / (1.f + __expf(-v));
            const int col = coff + n0 + wn + ni * 16 + qrow;
            if (OUT_BF16)
                ((__bf16*)C)[(size_t)row * ldc + col] = (__bf16)v;
            else
                ((float*)C)[(size_t)row * ldc + col] = v;
        }
    }
}

// ---------------------------------------------------------------------------
// attn_fused: 512-thread blocks.
// Blocks 0..1023: global MHA split-K x2 partials, 8 waves x 16 q = 128 q/blk,
//   16 key-chunks/block. Single-barrier double-buffered K-loop (LDS 35.8 KB;
//   4 blocks/CU is thread-capped so the double buffer costs no occupancy).
// Blocks 1024..5119: local window-5 MHA -> acat cols 256-511.
// ---------------------------------------------------------------------------
__global__ __launch_bounds__(512) void attn_fused(
    const __bf16* __restrict__ qkv, __bf16* __restrict__ Op,
    float* __restrict__ Lp, __bf16* __restrict__ acat)
{
    __shared__ __bf16 Kl[2][64 * 32];
    __shared__ __bf16 Vt[2][32 * 72];
    __shared__ __bf16 Pl[8][16 * 72];

    const int t = threadIdx.x;
    const int lane = t & 63;
    const int wv = t >> 6;          // 0..7

    if (blockIdx.x < 1024) {
        const int bid = blockIdx.x;
        const int sp = bid & 1;
        const int qc = (bid >> 1) & 15;
        const int h  = (bid >> 5) & 7;
        const int b  = bid >> 8;
        const int bS = b * Ss;
        const int q0 = qc * 128;

        const int qrow = lane & 15;
        const int quad = lane >> 4;
        const float cQ = 1.4426950408889634f * 0.17677669529663687f; // log2e/sqrt(32)

        bf16x8 qf;
        {
            bf16x8 qraw = *(const bf16x8*)(qkv +
                (size_t)(bS + q0 + wv * 16 + qrow) * QSTR + h * 32 + quad * 8);
#pragma unroll
            for (int i = 0; i < 8; i++) qf[i] = (__bf16)((float)qraw[i] * cQ);
        }
        bf16x8 ones;
#pragma unroll
        for (int i = 0; i < 8; i++) ones[i] = (__bf16)1.0f;

        f32x4 o0 = {0.f, 0.f, 0.f, 0.f};
        f32x4 o1 = {0.f, 0.f, 0.f, 0.f};
        f32x4 lac = {0.f, 0.f, 0.f, 0.f};
        const f32x4 z = {0.f, 0.f, 0.f, 0.f};

        const int kc_c = wv * 64 + lane;
        const int kkey = kc_c >> 2, kdg = kc_c & 3;
        const int vkey = t & 63, vq = t >> 6;   // V: key, dim group of 4
        const int kc0 = sp * 16;

        // prologue: prefetch chunk 0 (V into regs, K via glds into Kl[0])
        bf16x4 vreg = *(const bf16x4*)(qkv +
            (size_t)(bS + kc0 * 64 + vkey) * QSTR + 512 + h * 32 + vq * 4);
        if (wv < 4)
            glds16(qkv + (size_t)(bS + kc0 * 64 + kkey) * QSTR + 256 + h * 32 + kdg * 8,
                   &Kl[0][wv * 512]);

        for (int i = 0; i < 16; i++) {
            const int cur = i & 1;
#pragma unroll
            for (int e = 0; e < 4; e++) Vt[cur][(vq * 4 + e) * 72 + vkey] = vreg[e];
            __syncthreads();
            const int nx = (i < 15) ? (kc0 + i + 1) : (kc0 + 15);
            vreg = *(const bf16x4*)(qkv +
                (size_t)(bS + nx * 64 + vkey) * QSTR + 512 + h * 32 + vq * 4);
            if (i < 15 && wv < 4)
                glds16(qkv + (size_t)(bS + nx * 64 + kkey) * QSTR + 256 + h * 32 + kdg * 8,
                       &Kl[1 - cur][wv * 512]);

            f32x4 s[4];
#pragma unroll
            for (int kg = 0; kg < 4; kg++) {
                bf16x8 kf = *(const bf16x8*)&Kl[cur][(kg * 16 + qrow) * 32 + quad * 8];
                s[kg] = __builtin_amdgcn_mfma_f32_16x16x32_bf16(kf, qf, z, 0, 0, 0);
            }
#pragma unroll
            for (int kg = 0; kg < 4; kg++) {
                bf16x4 pk;
                pk[0] = (__bf16)exp2f(s[kg][0]);
                pk[1] = (__bf16)exp2f(s[kg][1]);
                pk[2] = (__bf16)exp2f(s[kg][2]);
                pk[3] = (__bf16)exp2f(s[kg][3]);
                *(bf16x4*)&Pl[wv][qrow * 72 + kg * 16 + quad * 4] = pk;
            }
            bf16x8 pf0 = *(const bf16x8*)&Pl[wv][qrow * 72 + quad * 8];
            bf16x8 pf1 = *(const bf16x8*)&Pl[wv][qrow * 72 + 32 + quad * 8];
            bf16x8 vf00 = *(const bf16x8*)&Vt[cur][qrow * 72 + quad * 8];
            bf16x8 vf01 = *(const bf16x8*)&Vt[cur][qrow * 72 + 32 + quad * 8];
            bf16x8 vf10 = *(const bf16x8*)&Vt[cur][(16 + qrow) * 72 + quad * 8];
            bf16x8 vf11 = *(const bf16x8*)&Vt[cur][(16 + qrow) * 72 + 32 + quad * 8];
            o0 = __builtin_amdgcn_mfma_f32_16x16x32_bf16(vf00, pf0, o0, 0, 0, 0);
            o1 = __builtin_amdgcn_mfma_f32_16x16x32_bf16(vf10, pf0, o1, 0, 0, 0);
            lac = __builtin_amdgcn_mfma_f32_16x16x32_bf16(ones, pf0, lac, 0, 0, 0);
            o0 = __builtin_amdgcn_mfma_f32_16x16x32_bf16(vf01, pf1, o0, 0, 0, 0);
            o1 = __builtin_amdgcn_mfma_f32_16x16x32_bf16(vf11, pf1, o1, 0, 0, 0);
            lac = __builtin_amdgcn_mfma_f32_16x16x32_bf16(ones, pf1, lac, 0, 0, 0);
        }

        const int gid = (b * 8 + h) * 2048 + q0 + wv * 16 + qrow;
        __bf16* po = Op + (size_t)sp * 2097152 + (size_t)gid * 32;
        bf16x4 w0, w1;
#pragma unroll
        for (int r = 0; r < 4; r++) { w0[r] = (__bf16)o0[r]; w1[r] = (__bf16)o1[r]; }
        *(bf16x4*)&po[quad * 4]      = w0;
        *(bf16x4*)&po[16 + quad * 4] = w1;
        if (quad == 0) Lp[sp * 65536 + gid] = lac[0];
    } else {
        const int w = (blockIdx.x - 1024) * 8 + wv;
        const int b = w >> 13;
        const int rem = w & 8191;
        const int s = rem >> 2;
        const int h = rem & 3;

        const float q = (float)qkv[(size_t)(b * Ss + s) * QSTR + 768 + h * 64 + lane];
        float sc[5], vv[5];
#pragma unroll
        for (int j = 0; j < 5; j++) {
            int pos = s + j - 2;
            bool valid = (pos >= 0) && (pos < Ss);
            int cpos = valid ? pos : 0;
            const size_t rb = (size_t)(b * Ss + cpos) * QSTR;
            float kj = valid ? (float)qkv[rb + 1024 + h * 64 + lane] : 0.f;
            vv[j] = valid ? (float)qkv[rb + 1280 + h * 64 + lane] : 0.f;
            float p = q * kj;
#pragma unroll
            for (int off = 32; off > 0; off >>= 1) p += __shfl_xor(p, off, 64);
            sc[j] = valid ? p * 0.125f : -1e30f;
        }
        float m = sc[0];
#pragma unroll
        for (int j = 1; j < 5; j++) m = fmaxf(m, sc[j]);
        float l = 0.f, o = 0.f;
#pragma unroll
        for (int j = 0; j < 5; j++) {
            float p = __expf(sc[j] - m);
            l += p; o += p * vv[j];
        }
        acat[(size_t)(b * Ss + s) * 512 + 256 + h * 64 + lane] = (__bf16)(o / l);
    }
}

// ---------------------------------------------------------------------------
// attn_combine: 2 bf16 split partials -> acat cols 0-255.
// ---------------------------------------------------------------------------
__global__ __launch_bounds__(256) void attn_combine(
    const __bf16* __restrict__ Op, const float* __restrict__ Lp,
    __bf16* __restrict__ acat)
{
    const int t = blockIdx.x * 256 + threadIdx.x;   // 0 .. 524287
    const int gid = t >> 3;
    const int dg = t & 7;
    const int b = gid >> 14;
    const int h = (gid >> 11) & 7;
    const int q = gid & 2047;

    const float li = 1.f / (Lp[gid] + Lp[65536 + gid]);
    const __bf16* base = Op + (size_t)gid * 32 + dg * 4;
    bf16x4 a0 = *(const bf16x4*)&base[0];
    bf16x4 a1 = *(const bf16x4*)&base[2097152];
    bf16x4 r;
#pragma unroll
    for (int i = 0; i < 4; i++)
        r[i] = (__bf16)(((float)a0[i] + (float)a1[i]) * li);
    *(bf16x4*)&acat[(size_t)(b * Ss + q) * 512 + h * 32 + dg * 4] = r;
}

// ---------------------------------------------------------------------------
// out = LayerNorm(a + r) * g + be over last dim (256). Wave per token.
// a fp32, r bf16. ob optional bf16 copy.
// ---------------------------------------------------------------------------
__global__ __launch_bounds__(256) void ln_residual(
    const float* __restrict__ a, const __bf16* __restrict__ r,
    const float* __restrict__ g, const float* __restrict__ be,
    float* __restrict__ out, __bf16* __restrict__ ob)
{
    const int lane = threadIdx.x & 63;
    const int tok = blockIdx.x * 4 + (threadIdx.x >> 6);
    float4 xa = ((const float4*)a)[(size_t)tok * 64 + lane];
    bf16x4 xr = *(const bf16x4*)&r[(size_t)tok * 256 + lane * 4];
    float4 x;
    x.x = xa.x + (float)xr[0]; x.y = xa.y + (float)xr[1];
    x.z = xa.z + (float)xr[2]; x.w = xa.w + (float)xr[3];
    float sum = x.x + x.y + x.z + x.w;
#pragma unroll
    for (int off = 32; off > 0; off >>= 1) sum += __shfl_xor(sum, off, 64);
    float mu = sum * (1.f / 256.f);
    float4 c;
    c.x = x.x - mu; c.y = x.y - mu; c.z = x.z - mu; c.w = x.w - mu;
    float sq = c.x * c.x + c.y * c.y + c.z * c.z + c.w * c.w;
#pragma unroll
    for (int off = 32; off > 0; off >>= 1) sq += __shfl_xor(sq, off, 64);
    float rs = rsqrtf(sq * (1.f / 256.f) + 1e-5f);
    float4 gg = ((const float4*)g)[lane];
    float4 bb = ((const float4*)be)[lane];
    float4 o;
    o.x = c.x * rs * gg.x + bb.x; o.y = c.y * rs * gg.y + bb.y;
    o.z = c.z * rs * gg.z + bb.z; o.w = c.w * rs * gg.w + bb.w;
    ((float4*)out)[(size_t)tok * 64 + lane] = o;
    if (ob) {
        bf16x4 hh;
        hh[0] = (__bf16)o.x; hh[1] = (__bf16)o.y; hh[2] = (__bf16)o.z; hh[3] = (__bf16)o.w;
        *(bf16x4*)&ob[(size_t)tok * 256 + lane * 4] = hh;
    }
}

// ---------------------------------------------------------------------------
extern "C" void kernel_launch(void* const* d_in, const int* in_sizes, int n_in,
                              void* d_out, int out_size, void* d_ws, size_t ws_size,
                              hipStream_t stream)
{
    const float* x      = (const float*)d_in[0];
    const float* g_in_w = (const float*)d_in[1];
    const float* g_in_b = (const float*)d_in[2];
    const float* g_out_w= (const float*)d_in[3];
    const float* g_out_b= (const float*)d_in[4];
    const float* t_in_w = (const float*)d_in[5];
    const float* t_in_b = (const float*)d_in[6];
    const float* t_out_w= (const float*)d_in[7];
    const float* t_out_b= (const float*)d_in[8];
    const float* fus_w1 = (const float*)d_in[9];
    const float* fus_b1 = (const float*)d_in[10];
    const float* fus_w2 = (const float*)d_in[11];
    const float* fus_b2 = (const float*)d_in[12];
    const float* ffn_w1 = (const float*)d_in[13];
    const float* ffn_b1 = (const float*)d_in[14];
    const float* ffn_w2 = (const float*)d_in[15];
    const float* ffn_b2 = (const float*)d_in[16];
    const float* gn_g   = (const float*)d_in[17];
    const float* gn_b   = (const float*)d_in[18];
    const float* fn_g   = (const float*)d_in[19];
    const float* fn_b   = (const float*)d_in[20];
    float* out = (float*)d_out;
    float* ws  = (float*)d_ws;

    // ws layout in f32 slots (peak < 19,464,192 slots = 77.9 MB; 84 MB safe)
    __bf16* xb     = (__bf16*)(ws);                 // [0, 1048576)
    __bf16* wb     = (__bf16*)(ws + 1048576);       // [1048576, 1638400)
    __bf16* qkvgl  = (__bf16*)(ws + 1638400);       // [1638400, 7929856)  8192x1536
    __bf16* acat   = (__bf16*)(ws + 7929856);       // [7929856, 10027008) 8192x512
    __bf16* fcomb  = (__bf16*)(ws + 10027008);      // [10027008, 12124160) 8192x512
    __bf16* h1     = (__bf16*)(ws + 12124160);      // [12124160, 14221312) 8192x512
    __bf16* xfb    = (__bf16*)(ws + 14221312);      // [14221312, 15269888) 8192x256
    float*  x2     = ws + 16318464;                 // [16318464, 18415616) fp32
    __bf16* x2b    = (__bf16*)(ws + 18415616);      // [18415616, 19464192)
    __bf16* h2     = h1;                            // reuse
    __bf16* xffb   = xfb;                           // reuse
    // attention partials: live only between attn_fused and attn_combine.
    __bf16* Op = (__bf16*)(ws + 10027008);          // 2x65536x32 bf16 over fcomb+h1
    float*  Lp = ws + 18415616;                     // 2x65536 fp32 over x2b

    __bf16* w_gin  = wb;              // [1536x256] combined (g rows 0-767, t 768-1535)
    __bf16* w_gout = wb + 393216;
    __bf16* w_tout = wb + 458752;
    __bf16* w_f1   = wb + 524288;
    __bf16* w_f2   = wb + 786432;
    __bf16* w_n1   = wb + 917504;
    __bf16* w_n2   = wb + 1048576;

    CvtArgs ca;
    ca.src[0] = x;      ca.dst[0] = xb;
    ca.src[1] = g_in_w; ca.dst[1] = w_gin;
    ca.src[2] = t_in_w; ca.dst[2] = w_gin + 196608;
    ca.src[3] = g_out_w;ca.dst[3] = w_gout;
    ca.src[4] = t_out_w;ca.dst[4] = w_tout;
    ca.src[5] = fus_w1; ca.dst[5] = w_f1;
    ca.src[6] = fus_w2; ca.dst[6] = w_f2;
    ca.src[7] = ffn_w1; ca.dst[7] = w_n1;
    ca.src[8] = ffn_w2; ca.dst[8] = w_n2;
    int st[10] = {0, 1024, 1120, 1216, 1248, 1280, 1408, 1472, 1536, 1600};
    for (int i = 0; i < 10; i++) ca.start[i] = st[i];

    convert_all<<<dim3(1600), 256, 0, stream>>>(ca);

    // Combined QKV projection: M=8192, N=1536, K=256 -> qkvgl (128x128 tiles)
    gemm128<<<dim3(12, 64), 256, 0, stream>>>(
        xb, w_gin, g_in_b, t_in_b, 768, qkvgl, 256, QSTR);
    // Global attention partials split-K x2 (blocks 0-1023) + local (1024-5119)
    attn_fused<<<dim3(5120), 512, 0, stream>>>(qkvgl, Op, Lp, acat);
    // Combine partials -> acat cols 0-255
    attn_combine<<<dim3(2048), 256, 0, stream>>>(Op, Lp, acat);
    // Fused output projections (both halves in one launch) into fcomb
    gemm_small<false, true><<<dim3(8, 256), 256, 0, stream>>>(
        acat, w_gout, g_out_b, w_tout, t_out_b, 4, 256, 256, fcomb, 512, 256, 512);
    // Fusion MLP
    gemm_small<true,  true><<<dim3(8, 256), 256, 0, stream>>>(
        fcomb, w_f1, fus_b1, w_f1, fus_b1, 1 << 30, 0, 0, h1, 512, 512, 512);
    gemm_small<false, true><<<dim3(4, 256), 256, 0, stream>>>(
        h1, w_f2, fus_b2, w_f2, fus_b2, 1 << 30, 0, 0, xfb, 512, 512, 256);
    ln_residual<<<dim3(2048), 256, 0, stream>>>(x, xfb, gn_g, gn_b, x2, x2b);
    // FFN
    gemm_small<true,  true><<<dim3(8, 256), 256, 0, stream>>>(
        x2b, w_n1, ffn_b1, w_n1, ffn_b1, 1 << 30, 0, 0, h2, 256, 256, 512);
    gemm_small<false, true><<<dim3(4, 256), 256, 0, stream>>>(
        h2, w_n2, ffn_b2, w_n2, ffn_b2, 1 << 30, 0, 0, xffb, 512, 512, 256);
    ln_residual<<<dim3(2048), 256, 0, stream>>>(x2, xffb, fn_g, fn_b, out, nullptr);
}